// Round 1
// baseline (4907.927 us; speedup 1.0000x reference)
//
#include <hip/hip_runtime.h>

#define Bv 2
#define Tv 2048
#define Dv 1024
#define Hv 16
#define HDv 64
#define Lv 4
#define Vv 32000
#define DFFv 4096
#define BTv (Bv * Tv)

typedef __attribute__((ext_vector_type(8))) short bfrag_t;  // 8 x bf16 MFMA frag
typedef __attribute__((ext_vector_type(4))) float f4_t;

__device__ __forceinline__ unsigned short f2bf(float f) {
  union { float f; unsigned int u; } cv; cv.f = f;
  unsigned int u = cv.u;
  u += 0x7fffu + ((u >> 16) & 1u);
  return (unsigned short)(u >> 16);
}

// ---------- elementwise f32 -> bf16 ----------
__global__ __launch_bounds__(256) void k_cvt(const float* __restrict__ src,
                                             unsigned short* __restrict__ dst, int n4) {
  int i = blockIdx.x * 256 + threadIdx.x;
  if (i >= n4) return;
  float4 v = ((const float4*)src)[i];
  ushort4 o;
  o.x = f2bf(v.x); o.y = f2bf(v.y); o.z = f2bf(v.z); o.w = f2bf(v.w);
  ((ushort4*)dst)[i] = o;
}

// ---------- embedding gather (fp32 residual stream) ----------
__global__ __launch_bounds__(256) void k_embed(const int* __restrict__ idx,
                                               const float* __restrict__ emb,
                                               float* __restrict__ x) {
  int row = blockIdx.x;
  ((float4*)(x + (size_t)row * Dv))[threadIdx.x] =
      ((const float4*)(emb + (size_t)idx[row] * Dv))[threadIdx.x];
}

// ---------- transpose + convert: src R x C f32 -> dst C x R bf16 ----------
__global__ __launch_bounds__(256) void k_tcvt(const float* __restrict__ src,
                                              unsigned short* __restrict__ dst,
                                              int R, int C) {
  __shared__ float tile[32][33];
  int c0 = blockIdx.x * 32, r0 = blockIdx.y * 32;
  int tx = threadIdx.x & 31, ty = threadIdx.x >> 5;
#pragma unroll
  for (int i = 0; i < 32; i += 8)
    tile[ty + i][tx] = src[(size_t)(r0 + ty + i) * C + c0 + tx];
  __syncthreads();
#pragma unroll
  for (int i = 0; i < 32; i += 8)
    dst[(size_t)(c0 + ty + i) * R + r0 + tx] = f2bf(tile[tx][ty + i]);
}

// ---------- layernorm: f32 in, bf16 out (block per row, D=1024) ----------
__global__ __launch_bounds__(256) void k_ln(const float* __restrict__ x,
                                            const float* __restrict__ w,
                                            const float* __restrict__ b,
                                            unsigned short* __restrict__ out) {
  int row = blockIdx.x, tid = threadIdx.x;
  float4 v = ((const float4*)(x + (size_t)row * Dv))[tid];
  float s = v.x + v.y + v.z + v.w;
  float s2 = v.x * v.x + v.y * v.y + v.z * v.z + v.w * v.w;
#pragma unroll
  for (int off = 32; off > 0; off >>= 1) {
    s += __shfl_xor(s, off);
    s2 += __shfl_xor(s2, off);
  }
  __shared__ float rs[4], rq[4];
  int wv_ = tid >> 6;
  if ((tid & 63) == 0) { rs[wv_] = s; rq[wv_] = s2; }
  __syncthreads();
  s = rs[0] + rs[1] + rs[2] + rs[3];
  s2 = rq[0] + rq[1] + rq[2] + rq[3];
  float mean = s * (1.0f / Dv);
  float var = s2 * (1.0f / Dv) - mean * mean;
  float rstd = rsqrtf(var + 1e-5f);
  float4 wv4 = ((const float4*)w)[tid];
  float4 bv4 = ((const float4*)b)[tid];
  ushort4 o;
  o.x = f2bf((v.x - mean) * rstd * wv4.x + bv4.x);
  o.y = f2bf((v.y - mean) * rstd * wv4.y + bv4.y);
  o.z = f2bf((v.z - mean) * rstd * wv4.z + bv4.z);
  o.w = f2bf((v.w - mean) * rstd * wv4.w + bv4.w);
  ((ushort4*)(out + (size_t)row * Dv))[tid] = o;
}

// ---------- RoPE in-place on q and k (fp32), interleaved pairs ----------
__global__ __launch_bounds__(256) void k_rope(float* __restrict__ q, float* __restrict__ k) {
  int g = blockIdx.x * 256 + threadIdx.x;  // pair index, B*T*512 total
  int row = g >> 9;
  int p = g & 511;          // h*32 + i
  int t = row & (Tv - 1);
  int hi = p & 31;
  float freq = (float)exp((double)hi * -0.28782313662425572);  // -ln(10000)/32
  float ang = (float)t * freq;
  float sn, cs;
  sincosf(ang, &sn, &cs);
  size_t base = (size_t)row * Dv + (size_t)(p >> 5) * HDv + (size_t)hi * 2;
  float e = q[base], o = q[base + 1];
  q[base] = e * cs - o * sn;
  q[base + 1] = e * sn + o * cs;
  e = k[base]; o = k[base + 1];
  k[base] = e * cs - o * sn;
  k[base + 1] = e * sn + o * cs;
}

// ---------- causal flash attention, fp32 VALU, 64x64 tiles ----------
// q,k,v: (B*T, D) fp32 laid out [b*T+t][h*64+d]; y: bf16 same layout.
__global__ __launch_bounds__(256) void k_attn(const float* __restrict__ q,
                                              const float* __restrict__ k,
                                              const float* __restrict__ v,
                                              unsigned short* __restrict__ y) {
  int qt = blockIdx.x, h = blockIdx.y, b = blockIdx.z;
  __shared__ float qs[64][68], ks[64][68], vs[64][68];  // ks doubles as P after S-phase
  int tid = threadIdx.x;
  int bi = tid >> 4, bj = tid & 15;
  int i0 = bi * 4, c0 = bj * 4;
  size_t qbase = ((size_t)(b * Tv + qt * 64)) * Dv + h * HDv;
#pragma unroll
  for (int it = 0; it < 4; ++it) {
    int id = tid + 256 * it;
    int r = id >> 4, c4 = (id & 15) * 4;
    float4 val = *(const float4*)(q + qbase + (size_t)r * Dv + c4);
    val.x *= 0.125f; val.y *= 0.125f; val.z *= 0.125f; val.w *= 0.125f;  // 1/sqrt(64)
    *(float4*)&qs[r][c4] = val;
  }
  float m[4] = {-1e30f, -1e30f, -1e30f, -1e30f};
  float l[4] = {0.f, 0.f, 0.f, 0.f};
  float o[4][4] = {};
  for (int kt = 0; kt <= qt; ++kt) {
    __syncthreads();  // previous PV reads done before overwriting ks/vs
    size_t kbase = ((size_t)(b * Tv + kt * 64)) * Dv + h * HDv;
#pragma unroll
    for (int it = 0; it < 4; ++it) {
      int id = tid + 256 * it;
      int r = id >> 4, c4 = (id & 15) * 4;
      *(float4*)&ks[r][c4] = *(const float4*)(k + kbase + (size_t)r * Dv + c4);
      *(float4*)&vs[r][c4] = *(const float4*)(v + kbase + (size_t)r * Dv + c4);
    }
    __syncthreads();
    // S phase: rows i0..i0+3, keys j = bj + 16*jj (strided -> conflict-free LDS reads)
    float s[4][4] = {};
    for (int d4 = 0; d4 < 16; ++d4) {
      float4 qv[4], kv[4];
#pragma unroll
      for (int ii = 0; ii < 4; ++ii) qv[ii] = *(const float4*)&qs[i0 + ii][d4 * 4];
#pragma unroll
      for (int jj = 0; jj < 4; ++jj) kv[jj] = *(const float4*)&ks[bj + 16 * jj][d4 * 4];
#pragma unroll
      for (int ii = 0; ii < 4; ++ii)
#pragma unroll
        for (int jj = 0; jj < 4; ++jj)
          s[ii][jj] += qv[ii].x * kv[jj].x + qv[ii].y * kv[jj].y +
                       qv[ii].z * kv[jj].z + qv[ii].w * kv[jj].w;
    }
    if (kt == qt) {
#pragma unroll
      for (int ii = 0; ii < 4; ++ii)
#pragma unroll
        for (int jj = 0; jj < 4; ++jj)
          if (bj + 16 * jj > i0 + ii) s[ii][jj] = -1e30f;
    }
    __syncthreads();  // all ks reads done; ks storage becomes P
    float alpha[4];
#pragma unroll
    for (int ii = 0; ii < 4; ++ii) {
      float rmax = fmaxf(fmaxf(s[ii][0], s[ii][1]), fmaxf(s[ii][2], s[ii][3]));
#pragma unroll
      for (int msk = 1; msk < 16; msk <<= 1) rmax = fmaxf(rmax, __shfl_xor(rmax, msk));
      float mn = fmaxf(m[ii], rmax);
      alpha[ii] = expf(m[ii] - mn);
      m[ii] = mn;
      float psum = 0.f;
#pragma unroll
      for (int jj = 0; jj < 4; ++jj) {
        float pv = expf(s[ii][jj] - mn);
        s[ii][jj] = pv;
        psum += pv;
      }
#pragma unroll
      for (int msk = 1; msk < 16; msk <<= 1) psum += __shfl_xor(psum, msk);
      l[ii] = l[ii] * alpha[ii] + psum;
#pragma unroll
      for (int jj = 0; jj < 4; ++jj) ks[i0 + ii][bj + 16 * jj] = s[ii][jj];
    }
    __syncthreads();
#pragma unroll
    for (int ii = 0; ii < 4; ++ii)
#pragma unroll
      for (int cc = 0; cc < 4; ++cc) o[ii][cc] *= alpha[ii];
    for (int j4 = 0; j4 < 16; ++j4) {
      float4 pr[4], vr[4];
#pragma unroll
      for (int ii = 0; ii < 4; ++ii) pr[ii] = *(const float4*)&ks[i0 + ii][j4 * 4];
#pragma unroll
      for (int jj = 0; jj < 4; ++jj) vr[jj] = *(const float4*)&vs[j4 * 4 + jj][c0];
#pragma unroll
      for (int ii = 0; ii < 4; ++ii) {
        o[ii][0] += pr[ii].x * vr[0].x + pr[ii].y * vr[1].x + pr[ii].z * vr[2].x + pr[ii].w * vr[3].x;
        o[ii][1] += pr[ii].x * vr[0].y + pr[ii].y * vr[1].y + pr[ii].z * vr[2].y + pr[ii].w * vr[3].y;
        o[ii][2] += pr[ii].x * vr[0].z + pr[ii].y * vr[1].z + pr[ii].z * vr[2].z + pr[ii].w * vr[3].z;
        o[ii][3] += pr[ii].x * vr[0].w + pr[ii].y * vr[1].w + pr[ii].z * vr[2].w + pr[ii].w * vr[3].w;
      }
    }
  }
#pragma unroll
  for (int ii = 0; ii < 4; ++ii) {
    float inv = 1.0f / l[ii];
    size_t ybo = ((size_t)(b * Tv + qt * 64 + i0 + ii)) * Dv + h * HDv + c0;
    ushort4 ov;
    ov.x = f2bf(o[ii][0] * inv);
    ov.y = f2bf(o[ii][1] * inv);
    ov.z = f2bf(o[ii][2] * inv);
    ov.w = f2bf(o[ii][3] * inv);
    *(ushort4*)(y + ybo) = ov;
  }
}

// ---------- bf16 MFMA GEMM: C(MxN) = A(MxK) * Bt(NxK)^T, fp32 acc ----------
// 128x128 tile, BK=32, 4 waves each 64x64 (4x4 of 16x16x32 MFMA).
template <bool BIAS, bool RES, bool GELU, bool OUTF32, bool OUTBF16>
__global__ __launch_bounds__(256) void k_gemm(const unsigned short* __restrict__ A,
                                              const unsigned short* __restrict__ Bt,
                                              const float* __restrict__ bias,
                                              float* __restrict__ C,
                                              unsigned short* __restrict__ Cb,
                                              int M, int N, int K) {
  __shared__ unsigned short As[128 * 40];  // stride 40 (+8 pad) keeps b128 reads 2-way max
  __shared__ unsigned short Bs[128 * 40];
  int tid = threadIdx.x;
  int n0 = blockIdx.x * 128, m0 = blockIdx.y * 128;
  int lane = tid & 63, wave = tid >> 6;
  int wm = (wave >> 1) * 64, wn = (wave & 1) * 64;
  int lrow = lane & 15, lq = lane >> 4;
  f4_t zero = {0.f, 0.f, 0.f, 0.f};
  f4_t acc[4][4];
#pragma unroll
  for (int i = 0; i < 4; ++i)
#pragma unroll
    for (int j = 0; j < 4; ++j) acc[i][j] = zero;
  int sr = tid >> 2, sq = (tid & 3) * 8;
  for (int kk = 0; kk < K; kk += 32) {
#pragma unroll
    for (int it = 0; it < 2; ++it) {
      int r = sr + it * 64;
      *(uint4*)(As + r * 40 + sq) = *(const uint4*)(A + (size_t)(m0 + r) * K + kk + sq);
      *(uint4*)(Bs + r * 40 + sq) = *(const uint4*)(Bt + (size_t)(n0 + r) * K + kk + sq);
    }
    __syncthreads();
    bfrag_t af[4], bfv[4];
#pragma unroll
    for (int i = 0; i < 4; ++i) {
      af[i] = *(const bfrag_t*)(As + (wm + i * 16 + lrow) * 40 + lq * 8);
      bfv[i] = *(const bfrag_t*)(Bs + (wn + i * 16 + lrow) * 40 + lq * 8);
    }
#pragma unroll
    for (int i = 0; i < 4; ++i)
#pragma unroll
      for (int j = 0; j < 4; ++j)
        acc[i][j] = __builtin_amdgcn_mfma_f32_16x16x32_bf16(af[i], bfv[j], acc[i][j], 0, 0, 0);
    __syncthreads();
  }
#pragma unroll
  for (int i = 0; i < 4; ++i) {
#pragma unroll
    for (int j = 0; j < 4; ++j) {
      int gc = n0 + wn + j * 16 + lrow;
      float bv = BIAS ? bias[gc] : 0.0f;
#pragma unroll
      for (int r = 0; r < 4; ++r) {
        int gr = m0 + wm + i * 16 + lq * 4 + r;
        float val = acc[i][j][r] + bv;
        if (GELU) val = 0.5f * val * (1.0f + erff(val * 0.70710678118654752f));
        size_t ci = (size_t)gr * N + gc;
        if (RES) val += C[ci];
        if (OUTF32) C[ci] = val;
        if (OUTBF16) Cb[ci] = f2bf(val);
      }
    }
  }
}

extern "C" void kernel_launch(void* const* d_in, const int* in_sizes, int n_in,
                              void* d_out, int out_size, void* d_ws, size_t ws_size,
                              hipStream_t stream) {
  const int* idx = (const int*)d_in[0];
  const float* tok = (const float*)d_in[1];
  const float* ln1w = (const float*)d_in[2];
  const float* ln1b = (const float*)d_in[3];
  const float* Wq = (const float*)d_in[4];
  const float* Wk = (const float*)d_in[5];
  const float* Wv = (const float*)d_in[6];
  const float* Wp = (const float*)d_in[7];
  const float* ln2w = (const float*)d_in[8];
  const float* ln2b = (const float*)d_in[9];
  const float* W1 = (const float*)d_in[10];
  const float* b1 = (const float*)d_in[11];
  const float* W2 = (const float*)d_in[12];
  const float* b2 = (const float*)d_in[13];
  const float* lnfw = (const float*)d_in[14];
  const float* lnfb = (const float*)d_in[15];
  float* out = (float*)d_out;

  char* ws = (char*)d_ws;
  size_t off = 0;
  auto alloc = [&](size_t bytes) -> void* {
    void* p = ws + off;
    off += (bytes + 255) & ~(size_t)255;
    return p;
  };
  float* x = (float*)alloc((size_t)BTv * Dv * 4);
  unsigned short* hb = (unsigned short*)alloc((size_t)BTv * Dv * 2);
  float* qb = (float*)alloc((size_t)BTv * Dv * 4);
  float* kb = (float*)alloc((size_t)BTv * Dv * 4);
  float* vb = (float*)alloc((size_t)BTv * Dv * 4);
  unsigned short* yb = (unsigned short*)alloc((size_t)BTv * Dv * 2);
  unsigned short* ub = (unsigned short*)alloc((size_t)BTv * DFFv * 2);
  unsigned short* wqt = (unsigned short*)alloc((size_t)Dv * Dv * 2);
  unsigned short* wkt = (unsigned short*)alloc((size_t)Dv * Dv * 2);
  unsigned short* wvt = (unsigned short*)alloc((size_t)Dv * Dv * 2);
  unsigned short* wpt = (unsigned short*)alloc((size_t)Dv * Dv * 2);
  unsigned short* w1t = (unsigned short*)alloc((size_t)DFFv * Dv * 2);
  unsigned short* w2t = (unsigned short*)alloc((size_t)Dv * DFFv * 2);
  unsigned short* embb = (unsigned short*)alloc((size_t)Vv * Dv * 2);

  k_cvt<<<(Vv * Dv / 4 + 255) / 256, 256, 0, stream>>>(tok, embb, Vv * Dv / 4);
  k_embed<<<BTv, 256, 0, stream>>>(idx, tok, x);
  for (int l = 0; l < Lv; ++l) {
    k_tcvt<<<dim3(Dv / 32, Dv / 32), 256, 0, stream>>>(Wq + (size_t)l * Dv * Dv, wqt, Dv, Dv);
    k_tcvt<<<dim3(Dv / 32, Dv / 32), 256, 0, stream>>>(Wk + (size_t)l * Dv * Dv, wkt, Dv, Dv);
    k_tcvt<<<dim3(Dv / 32, Dv / 32), 256, 0, stream>>>(Wv + (size_t)l * Dv * Dv, wvt, Dv, Dv);
    k_tcvt<<<dim3(Dv / 32, Dv / 32), 256, 0, stream>>>(Wp + (size_t)l * Dv * Dv, wpt, Dv, Dv);
    k_tcvt<<<dim3(DFFv / 32, Dv / 32), 256, 0, stream>>>(W1 + (size_t)l * Dv * DFFv, w1t, Dv, DFFv);
    k_tcvt<<<dim3(Dv / 32, DFFv / 32), 256, 0, stream>>>(W2 + (size_t)l * DFFv * Dv, w2t, DFFv, Dv);
    k_ln<<<BTv, 256, 0, stream>>>(x, ln1w + l * Dv, ln1b + l * Dv, hb);
    k_gemm<false, false, false, true, false><<<dim3(Dv / 128, BTv / 128), 256, 0, stream>>>(
        hb, wqt, nullptr, qb, nullptr, BTv, Dv, Dv);
    k_gemm<false, false, false, true, false><<<dim3(Dv / 128, BTv / 128), 256, 0, stream>>>(
        hb, wkt, nullptr, kb, nullptr, BTv, Dv, Dv);
    k_gemm<false, false, false, true, false><<<dim3(Dv / 128, BTv / 128), 256, 0, stream>>>(
        hb, wvt, nullptr, vb, nullptr, BTv, Dv, Dv);
    k_rope<<<(BTv * 512) / 256, 256, 0, stream>>>(qb, kb);
    k_attn<<<dim3(Tv / 64, Hv, Bv), 256, 0, stream>>>(qb, kb, vb, yb);
    k_gemm<false, true, false, true, false><<<dim3(Dv / 128, BTv / 128), 256, 0, stream>>>(
        yb, wpt, nullptr, x, nullptr, BTv, Dv, Dv);
    k_ln<<<BTv, 256, 0, stream>>>(x, ln2w + l * Dv, ln2b + l * Dv, hb);
    k_gemm<true, false, true, false, true><<<dim3(DFFv / 128, BTv / 128), 256, 0, stream>>>(
        hb, w1t, b1 + l * DFFv, nullptr, ub, BTv, DFFv, Dv);
    k_gemm<true, true, false, true, false><<<dim3(Dv / 128, BTv / 128), 256, 0, stream>>>(
        ub, w2t, b2 + l * Dv, x, nullptr, BTv, Dv, DFFv);
  }
  k_ln<<<BTv, 256, 0, stream>>>(x, lnfw, lnfb, hb);
  k_gemm<false, false, false, true, false><<<dim3(Vv / 128, BTv / 128), 256, 0, stream>>>(
      hb, embb, nullptr, out, nullptr, BTv, Vv, Dv);
  (void)in_sizes; (void)n_in; (void)out_size; (void)ws_size;
}